// Round 6
// baseline (493.031 us; speedup 1.0000x reference)
//
#include <hip/hip_runtime.h>
#include <stdint.h>

// STGraphConstructor: C[b] = tanh(relu(E[b] @ E[b]^T)), E = concat(spatial, temporal)
// B=16, N=2048, T=168, D=64, M=2216. fp32 in/out.
// R11 = R10 minus nontemporal stores (post-mortem: nt/evict-first caused
// partial-line evict+refetch -> FETCH ballooned to 310MB (= output size!) and
// WRITE to 430MB; strictly worse). Kept from R10, now cleanly testable:
//   - XCD b-clustering: flat grid, b = 2*(lid&7)+((lid>>3)&1); each XCD serves
//     2 batches -> ws working set 1.15MB < 4MB L2 (R9 showed 86MB/pass fetch
//     when all 16 batches shared every L2).
//   - 2x occupancy: col range split in halves -> 2240 blocks (8.75/CU),
//     __launch_bounds__(256,8). R10 measured Occupancy 75% (vs 36% in R9).
// Store path = R8/R9's proven one: plain scalar dwords, half-wave = 128B run,
// WRITE_SIZE confirmed 337MB (no amplification).
// Numerics bit-identical to R5-R10.

constexpr int Bsz = 16;
constexpr int Nsp = 2048;
constexpr int Ttm = 168;
constexpr int D   = 64;
constexpr int M   = Nsp + Ttm;                // 2216
constexpr int NG32 = (M + 31) / 32;           // 70 row/col groups of 32
constexpr int NG   = 72;                      // groups allocated in ws (zero-padded)
constexpr int GRP_SH   = 4 * 64 * 8;          // shorts per group: 4 ks * 64 lanes * 8
constexpr int BATCH_SH = NG * GRP_SH;         // 147456 shorts / batch / plane
constexpr int PLANE_SH = Bsz * BATCH_SH;      // 2359296 shorts / plane
constexpr size_t WS_NEED = (size_t)2 * PLANE_SH * sizeof(unsigned short); // 9.4 MB

typedef __attribute__((ext_vector_type(8)))  short bf16x8;   // 8 bf16 = 4 VGPRs
typedef __attribute__((ext_vector_type(16))) float f32x16;   // 32x32 acc

__device__ inline void split8(const float4& a, const float4& b,
                              bf16x8& hi, bf16x8& lo) {
    float x[8] = {a.x, a.y, a.z, a.w, b.x, b.y, b.z, b.w};
    #pragma unroll
    for (int i = 0; i < 8; ++i) {
        union { float f; uint32_t u; } v; v.f = x[i];
        uint32_t hu = (v.u + 0x7FFFu + ((v.u >> 16) & 1u)) >> 16;   // RNE to bf16
        union { uint32_t u; float f; } hf; hf.u = hu << 16;
        union { float f; uint32_t u; } r; r.f = x[i] - hf.f;        // exact residual
        uint32_t lu = (r.u + 0x7FFFu + ((r.u >> 16) & 1u)) >> 16;
        hi[i] = (short)hu;
        lo[i] = (short)lu;
    }
}

__device__ inline float act_tanh_relu(float x) {
    const float xr = fmaxf(x, 0.0f);
    const float e  = __expf(2.0f * xr);                  // inf for large x -> 1
    const float r  = __builtin_amdgcn_rcpf(e + 1.0f);    // ~1 ulp, rcp(inf)=0
    return 1.0f - 2.0f * r;
}

// ---------------- kernel 1: fp32 E -> swizzled hi/lo bf16 planes ----------------
__global__ __launch_bounds__(256) void convert_kernel(
    const float* __restrict__ spatial,
    const float* __restrict__ temporal,
    unsigned short* __restrict__ ws)
{
    const int idx = blockIdx.x * 256 + threadIdx.x;   // 0 .. 16*72*4*64-1
    const int b  = idx / (NG * 4 * 64);
    const int r1 = idx % (NG * 4 * 64);
    const int g  = r1 / (4 * 64);
    const int r2 = r1 % (4 * 64);
    const int ks   = r2 >> 6;
    const int lane = r2 & 63;
    const int row  = 32 * g + (lane & 31);
    const int k0   = ks * 16 + 8 * (lane >> 5);

    float4 v0 = make_float4(0.f, 0.f, 0.f, 0.f), v1 = v0;
    if (row < M) {
        const float* src = (row < Nsp)
            ? spatial  + ((size_t)b * Nsp + row) * D
            : temporal + ((size_t)b * Ttm + (row - Nsp)) * D;
        v0 = *(const float4*)(src + k0);
        v1 = *(const float4*)(src + k0 + 4);
    }
    bf16x8 hi, lo;
    split8(v0, v1, hi, lo);

    const size_t o = (size_t)b * BATCH_SH + (size_t)g * GRP_SH + (ks * 64 + lane) * 8;
    *(bf16x8*)(ws + o)            = hi;
    *(bf16x8*)(ws + PLANE_SH + o) = lo;
}

// ---------------- kernel 2: row-panel MFMA main (R11) ----------------
// flat grid of 2240 blocks: (b clustered per XCD) x (70 row groups) x (2 col halves)
__global__ __launch_bounds__(256, 8) void stgraph_rowpanel(
    const unsigned short* __restrict__ ws,
    float* __restrict__ out)
{
    const int tid = threadIdx.x;
    const int lid = blockIdx.x;                  // 0..2239
    // XCD b-clustering: round-robin dispatch assumed (lid % 8 -> XCD).
    // Each XCD then serves b in {2*xcd, 2*xcd+1}: ws slice 1.15MB < 4MB L2.
    const int b  = 2 * (lid & 7) + ((lid >> 3) & 1);
    const int r  = lid >> 4;                     // 0..139
    const int g  = r % NG32;                     // row group: rows 32g..32g+31
    const int h  = r / NG32;                     // col half
    const int lo = h * 35;
    const int hi = lo + 35;                      // [lo, hi) col groups

    const int lane = tid & 63;
    const int w    = tid >> 6;
    const int l31  = lane & 31;
    const int lhi  = lane >> 5;

    const unsigned short* Hb = ws + (size_t)b * BATCH_SH;
    const unsigned short* Lb = Hb + PLANE_SH;

    // A fragments for this block's panel (all waves share the same 32 rows)
    bf16x8 ahi[4], alo[4];
    #pragma unroll
    for (int ks = 0; ks < 4; ++ks) {
        const int fo = (ks * 64 + lane) * 8;
        ahi[ks] = *(const bf16x8*)(Hb + (size_t)g * GRP_SH + fo);
        alo[ks] = *(const bf16x8*)(Lb + (size_t)g * GRP_SH + fo);
    }

    float* out_b = out + (size_t)b * M * M;

    // wave w walks ct = lo+w, lo+w+4, ... within its half.
    for (int ct = lo + w; ct < hi; ct += 4) {
        f32x16 acc = {};
        #pragma unroll
        for (int ks = 0; ks < 4; ++ks) {
            const int fo = (ks * 64 + lane) * 8;
            bf16x8 bhi = *(const bf16x8*)(Hb + (size_t)ct * GRP_SH + fo);
            bf16x8 blo = *(const bf16x8*)(Lb + (size_t)ct * GRP_SH + fo);
            acc = __builtin_amdgcn_mfma_f32_32x32x16_bf16(ahi[ks], bhi, acc, 0, 0, 0);
            acc = __builtin_amdgcn_mfma_f32_32x32x16_bf16(ahi[ks], blo, acc, 0, 0, 0);
            acc = __builtin_amdgcn_mfma_f32_32x32x16_bf16(alo[ks], bhi, acc, 0, 0, 0);
        }

        // C layout (m74/m101): col = lane&31, row = (r&3) + 8*(r>>2) + 4*lhi
        const int col = 32 * ct + l31;
        if (col < M) {
            #pragma unroll
            for (int rr = 0; rr < 16; ++rr) {
                const int grow = 32 * g + (rr & 3) + 8 * (rr >> 2) + 4 * lhi;
                if (grow < M)
                    out_b[(size_t)grow * M + col] = act_tanh_relu(acc[rr]);
            }
        }
    }
}

// ---------------- fallback (R6, self-contained) if ws too small ----------------
constexpr int TILE = 128;
constexpr int NT   = (M + TILE - 1) / TILE;   // 18 tiles
constexpr int NPAIR = NT * (NT + 1) / 2;      // 171 pairs

__global__ __launch_bounds__(256, 3) void stgraph_fallback(
    const float* __restrict__ spatial,
    const float* __restrict__ temporal,
    float* __restrict__ out)
{
    const int tid = threadIdx.x;
    const int b   = blockIdx.y;
    const int p = blockIdx.x;
    int ti = (int)((37.0f - sqrtf(1369.0f - 8.0f * (float)p)) * 0.5f);
    while (ti * (37 - ti) / 2 > p) --ti;
    while ((ti + 1) * (36 - ti) / 2 <= p) ++ti;
    const int tj = ti + (p - ti * (37 - ti) / 2);
    const bool diag = (ti == tj);

    const float* sp_b = spatial  + (size_t)b * Nsp * D;
    const float* tp_b = temporal + (size_t)b * Ttm * D;

    const int lane = tid & 63;
    const int w    = tid >> 6;
    const int l31  = lane & 31;
    const int lhi  = lane >> 5;

    const int giA = ti * TILE + 32 * w + l31;
    const float* rowA = nullptr;
    if (giA < M)
        rowA = (giA < Nsp) ? sp_b + (size_t)giA * D
                           : tp_b + (size_t)(giA - Nsp) * D;
    const float* rowB[4];
    #pragma unroll
    for (int t = 0; t < 4; ++t) {
        const int gj = tj * TILE + 32 * t + l31;
        rowB[t] = nullptr;
        if (gj < M)
            rowB[t] = (gj < Nsp) ? sp_b + (size_t)gj * D
                                 : tp_b + (size_t)(gj - Nsp) * D;
    }

    f32x16 acc[4] = {};
    #pragma unroll
    for (int ks = 0; ks < 4; ++ks) {
        const int ko = ks * 16 + 8 * lhi;
        float4 a0 = make_float4(0.f, 0.f, 0.f, 0.f), a1 = a0;
        if (rowA) { a0 = *(const float4*)(rowA + ko); a1 = *(const float4*)(rowA + ko + 4); }
        bf16x8 ahi, alo;
        split8(a0, a1, ahi, alo);
        #pragma unroll
        for (int t = 0; t < 4; ++t) {
            float4 b0 = make_float4(0.f, 0.f, 0.f, 0.f), b1 = b0;
            if (rowB[t]) { b0 = *(const float4*)(rowB[t] + ko); b1 = *(const float4*)(rowB[t] + ko + 4); }
            bf16x8 bhi, blo;
            split8(b0, b1, bhi, blo);
            acc[t] = __builtin_amdgcn_mfma_f32_32x32x16_bf16(ahi, bhi, acc[t], 0, 0, 0);
            acc[t] = __builtin_amdgcn_mfma_f32_32x32x16_bf16(ahi, blo, acc[t], 0, 0, 0);
            acc[t] = __builtin_amdgcn_mfma_f32_32x32x16_bf16(alo, bhi, acc[t], 0, 0, 0);
        }
    }

    float* out_b = out + (size_t)b * M * M;
    #pragma unroll
    for (int t = 0; t < 4; ++t) {
        const int gj = tj * TILE + 32 * t + l31;
        float v[16];
        #pragma unroll
        for (int r = 0; r < 16; ++r) v[r] = act_tanh_relu(acc[t][r]);
        if (gj < M) {
            #pragma unroll
            for (int r = 0; r < 16; ++r) {
                const int gi = ti * TILE + 32 * w + (r & 3) + 8 * (r >> 2) + 4 * lhi;
                if (gi < M) out_b[(size_t)gi * M + gj] = v[r];
            }
            if (!diag) {
                #pragma unroll
                for (int gq = 0; gq < 4; ++gq) {
                    const int gibase = ti * TILE + 32 * w + 8 * gq + 4 * lhi;
                    float4 w4 = make_float4(v[4 * gq + 0], v[4 * gq + 1],
                                            v[4 * gq + 2], v[4 * gq + 3]);
                    *(float4*)(&out_b[(size_t)gj * M + gibase]) = w4;
                }
            }
        }
    }
}

extern "C" void kernel_launch(void* const* d_in, const int* in_sizes, int n_in,
                              void* d_out, int out_size, void* d_ws, size_t ws_size,
                              hipStream_t stream) {
    const float* spatial  = (const float*)d_in[0];
    const float* temporal = (const float*)d_in[1];
    float* out = (float*)d_out;

    if (d_ws != nullptr && ws_size >= WS_NEED) {
        unsigned short* ws = (unsigned short*)d_ws;
        {
            dim3 block(256);
            dim3 grid((Bsz * NG * 4 * 64) / 256);   // 1152 blocks
            convert_kernel<<<grid, block, 0, stream>>>(spatial, temporal, ws);
        }
        {
            dim3 block(256);
            dim3 grid(16 * NG32 * 2);               // 2240 flat blocks
            stgraph_rowpanel<<<grid, block, 0, stream>>>(ws, out);
        }
    } else {
        dim3 block(256);
        dim3 grid(NPAIR, Bsz);
        stgraph_fallback<<<grid, block, 0, stream>>>(spatial, temporal, out);
    }
}

// Round 7
// 389.298 us; speedup vs baseline: 1.2665x; 1.2665x over previous
//
#include <hip/hip_runtime.h>
#include <stdint.h>

// STGraphConstructor: C[b] = tanh(relu(E[b] @ E[b]^T)), E = concat(spatial, temporal)
// B=16, N=2048, T=168, D=64, M=2216. fp32 in/out.
// R12: revert R10/R11's grid experiments (same-run arithmetic: clustering+flat
// grid cost ~85us vs R8 -- write locality of the 2D (g,b) order was the thing
// that worked; XCD-mapping premise unverified). Keep R8's order; attack R9's
// measured latency-boundedness (MfmaUtil 10%, VALUBusy 22%, FETCH 86MB ws
// re-fetch) with per-wave ILP instead:
//   - 2D grid (x = (g,h), y = b), g = x>>1, h = x&1: consecutive blocks write
//     one contiguous panel of one batch (R8's proven write pattern), 2240
//     blocks for tail; __launch_bounds__(256,4).
//   - software prefetch depth 2: next col-group's 8 B-frag loads issued
//     BEFORE the current MFMA+stores -> per-wave stall = latency - compute
//     instead of full latency. ~120 VGPR, fits the 128 budget.
//   - plain scalar stores (R9 proved no write amplification; R10 proved nt
//     stores catastrophically backfire via partial-line evict+refetch).
// Numerics bit-identical to R5-R11.

constexpr int Bsz = 16;
constexpr int Nsp = 2048;
constexpr int Ttm = 168;
constexpr int D   = 64;
constexpr int M   = Nsp + Ttm;                // 2216
constexpr int NG32 = (M + 31) / 32;           // 70 row/col groups of 32
constexpr int NG   = 72;                      // groups allocated in ws (zero-padded)
constexpr int GRP_SH   = 4 * 64 * 8;          // shorts per group: 4 ks * 64 lanes * 8
constexpr int BATCH_SH = NG * GRP_SH;         // 147456 shorts / batch / plane
constexpr int PLANE_SH = Bsz * BATCH_SH;      // 2359296 shorts / plane
constexpr size_t WS_NEED = (size_t)2 * PLANE_SH * sizeof(unsigned short); // 9.4 MB

typedef __attribute__((ext_vector_type(8)))  short bf16x8;   // 8 bf16 = 4 VGPRs
typedef __attribute__((ext_vector_type(16))) float f32x16;   // 32x32 acc

__device__ inline void split8(const float4& a, const float4& b,
                              bf16x8& hi, bf16x8& lo) {
    float x[8] = {a.x, a.y, a.z, a.w, b.x, b.y, b.z, b.w};
    #pragma unroll
    for (int i = 0; i < 8; ++i) {
        union { float f; uint32_t u; } v; v.f = x[i];
        uint32_t hu = (v.u + 0x7FFFu + ((v.u >> 16) & 1u)) >> 16;   // RNE to bf16
        union { uint32_t u; float f; } hf; hf.u = hu << 16;
        union { float f; uint32_t u; } r; r.f = x[i] - hf.f;        // exact residual
        uint32_t lu = (r.u + 0x7FFFu + ((r.u >> 16) & 1u)) >> 16;
        hi[i] = (short)hu;
        lo[i] = (short)lu;
    }
}

__device__ inline float act_tanh_relu(float x) {
    const float xr = fmaxf(x, 0.0f);
    const float e  = __expf(2.0f * xr);                  // inf for large x -> 1
    const float r  = __builtin_amdgcn_rcpf(e + 1.0f);    // ~1 ulp, rcp(inf)=0
    return 1.0f - 2.0f * r;
}

// ---------------- kernel 1: fp32 E -> swizzled hi/lo bf16 planes ----------------
__global__ __launch_bounds__(256) void convert_kernel(
    const float* __restrict__ spatial,
    const float* __restrict__ temporal,
    unsigned short* __restrict__ ws)
{
    const int idx = blockIdx.x * 256 + threadIdx.x;   // 0 .. 16*72*4*64-1
    const int b  = idx / (NG * 4 * 64);
    const int r1 = idx % (NG * 4 * 64);
    const int g  = r1 / (4 * 64);
    const int r2 = r1 % (4 * 64);
    const int ks   = r2 >> 6;
    const int lane = r2 & 63;
    const int row  = 32 * g + (lane & 31);
    const int k0   = ks * 16 + 8 * (lane >> 5);

    float4 v0 = make_float4(0.f, 0.f, 0.f, 0.f), v1 = v0;
    if (row < M) {
        const float* src = (row < Nsp)
            ? spatial  + ((size_t)b * Nsp + row) * D
            : temporal + ((size_t)b * Ttm + (row - Nsp)) * D;
        v0 = *(const float4*)(src + k0);
        v1 = *(const float4*)(src + k0 + 4);
    }
    bf16x8 hi, lo;
    split8(v0, v1, hi, lo);

    const size_t o = (size_t)b * BATCH_SH + (size_t)g * GRP_SH + (ks * 64 + lane) * 8;
    *(bf16x8*)(ws + o)            = hi;
    *(bf16x8*)(ws + PLANE_SH + o) = lo;
}

// ---------------- kernel 2: row-panel MFMA main (R12) ----------------
// grid: x = 140 (g = x>>1 panel, h = x&1 col half), y = 16 batches.
__global__ __launch_bounds__(256, 4) void stgraph_rowpanel(
    const unsigned short* __restrict__ ws,
    float* __restrict__ out)
{
    const int tid = threadIdx.x;
    const int bx  = blockIdx.x;                  // 0..139
    const int b   = blockIdx.y;
    const int g   = bx >> 1;                     // row group: rows 32g..32g+31
    const int h   = bx & 1;                      // col half
    const int clo = h * 35;
    const int chi = clo + 35;                    // [clo, chi) col groups

    const int lane = tid & 63;
    const int w    = tid >> 6;
    const int l31  = lane & 31;
    const int lhi  = lane >> 5;

    const unsigned short* Hb = ws + (size_t)b * BATCH_SH;
    const unsigned short* Lb = Hb + PLANE_SH;

    // A fragments for this block's panel (all waves share the same 32 rows)
    bf16x8 ahi[4], alo[4];
    #pragma unroll
    for (int ks = 0; ks < 4; ++ks) {
        const int fo = (ks * 64 + lane) * 8;
        ahi[ks] = *(const bf16x8*)(Hb + (size_t)g * GRP_SH + fo);
        alo[ks] = *(const bf16x8*)(Lb + (size_t)g * GRP_SH + fo);
    }

    float* out_b = out + (size_t)b * M * M;

    // wave w walks ct = clo+w, clo+w+4, ... within its half, with the next
    // iteration's B fragments prefetched before the current MFMA+stores.
    int ct = clo + w;                            // < chi always (35 > 4)

    bf16x8 cbhi[4], cblo[4];
    #pragma unroll
    for (int ks = 0; ks < 4; ++ks) {
        const int fo = (ks * 64 + lane) * 8;
        cbhi[ks] = *(const bf16x8*)(Hb + (size_t)ct * GRP_SH + fo);
        cblo[ks] = *(const bf16x8*)(Lb + (size_t)ct * GRP_SH + fo);
    }

    while (true) {
        const int nct  = ct + 4;
        const bool more = (nct < chi);           // wave-uniform branch

        bf16x8 nbhi[4], nblo[4];
        if (more) {
            #pragma unroll
            for (int ks = 0; ks < 4; ++ks) {
                const int fo = (ks * 64 + lane) * 8;
                nbhi[ks] = *(const bf16x8*)(Hb + (size_t)nct * GRP_SH + fo);
                nblo[ks] = *(const bf16x8*)(Lb + (size_t)nct * GRP_SH + fo);
            }
        }

        f32x16 acc = {};
        #pragma unroll
        for (int ks = 0; ks < 4; ++ks) {
            acc = __builtin_amdgcn_mfma_f32_32x32x16_bf16(ahi[ks], cbhi[ks], acc, 0, 0, 0);
            acc = __builtin_amdgcn_mfma_f32_32x32x16_bf16(ahi[ks], cblo[ks], acc, 0, 0, 0);
            acc = __builtin_amdgcn_mfma_f32_32x32x16_bf16(alo[ks], cbhi[ks], acc, 0, 0, 0);
        }

        // C layout (m74/m101): col = lane&31, row = (r&3) + 8*(r>>2) + 4*lhi
        const int col = 32 * ct + l31;
        if (col < M) {
            #pragma unroll
            for (int rr = 0; rr < 16; ++rr) {
                const int grow = 32 * g + (rr & 3) + 8 * (rr >> 2) + 4 * lhi;
                if (grow < M)
                    out_b[(size_t)grow * M + col] = act_tanh_relu(acc[rr]);
            }
        }

        if (!more) break;
        #pragma unroll
        for (int ks = 0; ks < 4; ++ks) { cbhi[ks] = nbhi[ks]; cblo[ks] = nblo[ks]; }
        ct = nct;
    }
}

// ---------------- fallback (R6, self-contained) if ws too small ----------------
constexpr int TILE = 128;
constexpr int NT   = (M + TILE - 1) / TILE;   // 18 tiles
constexpr int NPAIR = NT * (NT + 1) / 2;      // 171 pairs

__global__ __launch_bounds__(256, 3) void stgraph_fallback(
    const float* __restrict__ spatial,
    const float* __restrict__ temporal,
    float* __restrict__ out)
{
    const int tid = threadIdx.x;
    const int b   = blockIdx.y;
    const int p = blockIdx.x;
    int ti = (int)((37.0f - sqrtf(1369.0f - 8.0f * (float)p)) * 0.5f);
    while (ti * (37 - ti) / 2 > p) --ti;
    while ((ti + 1) * (36 - ti) / 2 <= p) ++ti;
    const int tj = ti + (p - ti * (37 - ti) / 2);
    const bool diag = (ti == tj);

    const float* sp_b = spatial  + (size_t)b * Nsp * D;
    const float* tp_b = temporal + (size_t)b * Ttm * D;

    const int lane = tid & 63;
    const int w    = tid >> 6;
    const int l31  = lane & 31;
    const int lhi  = lane >> 5;

    const int giA = ti * TILE + 32 * w + l31;
    const float* rowA = nullptr;
    if (giA < M)
        rowA = (giA < Nsp) ? sp_b + (size_t)giA * D
                           : tp_b + (size_t)(giA - Nsp) * D;
    const float* rowB[4];
    #pragma unroll
    for (int t = 0; t < 4; ++t) {
        const int gj = tj * TILE + 32 * t + l31;
        rowB[t] = nullptr;
        if (gj < M)
            rowB[t] = (gj < Nsp) ? sp_b + (size_t)gj * D
                                 : tp_b + (size_t)(gj - Nsp) * D;
    }

    f32x16 acc[4] = {};
    #pragma unroll
    for (int ks = 0; ks < 4; ++ks) {
        const int ko = ks * 16 + 8 * lhi;
        float4 a0 = make_float4(0.f, 0.f, 0.f, 0.f), a1 = a0;
        if (rowA) { a0 = *(const float4*)(rowA + ko); a1 = *(const float4*)(rowA + ko + 4); }
        bf16x8 ahi, alo;
        split8(a0, a1, ahi, alo);
        #pragma unroll
        for (int t = 0; t < 4; ++t) {
            float4 b0 = make_float4(0.f, 0.f, 0.f, 0.f), b1 = b0;
            if (rowB[t]) { b0 = *(const float4*)(rowB[t] + ko); b1 = *(const float4*)(rowB[t] + ko + 4); }
            bf16x8 bhi, blo;
            split8(b0, b1, bhi, blo);
            acc[t] = __builtin_amdgcn_mfma_f32_32x32x16_bf16(ahi, bhi, acc[t], 0, 0, 0);
            acc[t] = __builtin_amdgcn_mfma_f32_32x32x16_bf16(ahi, blo, acc[t], 0, 0, 0);
            acc[t] = __builtin_amdgcn_mfma_f32_32x32x16_bf16(alo, bhi, acc[t], 0, 0, 0);
        }
    }

    float* out_b = out + (size_t)b * M * M;
    #pragma unroll
    for (int t = 0; t < 4; ++t) {
        const int gj = tj * TILE + 32 * t + l31;
        float v[16];
        #pragma unroll
        for (int r = 0; r < 16; ++r) v[r] = act_tanh_relu(acc[t][r]);
        if (gj < M) {
            #pragma unroll
            for (int r = 0; r < 16; ++r) {
                const int gi = ti * TILE + 32 * w + (r & 3) + 8 * (r >> 2) + 4 * lhi;
                if (gi < M) out_b[(size_t)gi * M + gj] = v[r];
            }
            if (!diag) {
                #pragma unroll
                for (int gq = 0; gq < 4; ++gq) {
                    const int gibase = ti * TILE + 32 * w + 8 * gq + 4 * lhi;
                    float4 w4 = make_float4(v[4 * gq + 0], v[4 * gq + 1],
                                            v[4 * gq + 2], v[4 * gq + 3]);
                    *(float4*)(&out_b[(size_t)gj * M + gibase]) = w4;
                }
            }
        }
    }
}

extern "C" void kernel_launch(void* const* d_in, const int* in_sizes, int n_in,
                              void* d_out, int out_size, void* d_ws, size_t ws_size,
                              hipStream_t stream) {
    const float* spatial  = (const float*)d_in[0];
    const float* temporal = (const float*)d_in[1];
    float* out = (float*)d_out;

    if (d_ws != nullptr && ws_size >= WS_NEED) {
        unsigned short* ws = (unsigned short*)d_ws;
        {
            dim3 block(256);
            dim3 grid((Bsz * NG * 4 * 64) / 256);   // 1152 blocks
            convert_kernel<<<grid, block, 0, stream>>>(spatial, temporal, ws);
        }
        {
            dim3 block(256);
            dim3 grid(2 * NG32, Bsz);               // 140 x 16
            stgraph_rowpanel<<<grid, block, 0, stream>>>(ws, out);
        }
    } else {
        dim3 block(256);
        dim3 grid(NPAIR, Bsz);
        stgraph_fallback<<<grid, block, 0, stream>>>(spatial, temporal, out);
    }
}